// Round 1
// baseline (439.646 us; speedup 1.0000x reference)
//
#include <hip/hip_runtime.h>
#include <math.h>

#define F 128

// ---------- helpers ----------
__device__ inline int read_idx(const int* ei, long long elem, int i64) {
    // edge_index may be int32 (JAX default, most likely) or int64; probe decides.
    return i64 ? (int)((const long long*)ei)[elem] : ei[elem];
}

// ---------- K1: init deg (self-loop weight 1.0), cnt=0, detect index dtype ----------
__global__ void k_init(float* deg, int* cnt, int* flag, const int* ei, int N) {
    int i = blockIdx.x * blockDim.x + threadIdx.x;
    if (i < N) { deg[i] = 1.0f; cnt[i] = 0; }
    if (i == 0) {
        // int64 little-endian: high words (odd int32 slots) of values < 2^31 are 0.
        int i64 = 1;
        for (int j = 0; j < 32; ++j) if (ei[2 * j + 1] != 0) { i64 = 0; break; }
        *flag = i64;
    }
}

// ---------- K2: weighted degree by col + per-col edge count ----------
__global__ void k_deg(const int* ei, const float* ew, float* deg, int* cnt,
                      const int* flag, int E) {
    int e = blockIdx.x * blockDim.x + threadIdx.x;
    if (e >= E) return;
    int i64 = *flag;
    int c = read_idx(ei, (long long)E + e, i64);
    atomicAdd(&deg[c], ew[e]);
    atomicAdd(&cnt[c], 1);
}

// ---------- K3: dinv = rsqrt(deg) in place (deg >= 1 always, self-loop) ----------
__global__ void k_rsqrt(float* deg, int N) {
    int i = blockIdx.x * blockDim.x + threadIdx.x;
    if (i < N) deg[i] = rsqrtf(deg[i]);
}

// ---------- K4: single-block exclusive scan of cnt -> off ----------
__global__ void k_scan(const int* cnt, int* off, int N) {
    __shared__ int sdata[1024];
    int tid = threadIdx.x;
    int run = 0;
    for (int base = 0; base < N; base += 1024) {
        int i = base + tid;
        int v = (i < N) ? cnt[i] : 0;
        sdata[tid] = v;
        __syncthreads();
        #pragma unroll
        for (int s = 1; s < 1024; s <<= 1) {
            int add = (tid >= s) ? sdata[tid - s] : 0;
            __syncthreads();
            sdata[tid] += add;
            __syncthreads();
        }
        int incl = sdata[tid];
        if (i < N) off[i] = run + incl - v;   // exclusive
        run += sdata[1023];
        __syncthreads();
    }
}

// ---------- K5: scatter edges into CSR buckets; off[] mutates to segment ends ----------
__global__ void k_scatter(const int* ei, const float* ew, const float* dinv,
                          int* off, int* erow, float* ewt, const int* flag, int E) {
    int e = blockIdx.x * blockDim.x + threadIdx.x;
    if (e >= E) return;
    int i64 = *flag;
    int r = read_idx(ei, e, i64);
    int c = read_idx(ei, (long long)E + e, i64);
    int pos = atomicAdd(&off[c], 1);
    erow[pos] = r;
    ewt[pos] = dinv[r] * ew[e] * dinv[c];
}

// ---------- K6: GRU weight evolution, one block per row i, 128 threads = j ----------
__global__ void k_evolve(const float* __restrict__ W0, const float* __restrict__ Wih,
                         const float* __restrict__ Whh, const float* __restrict__ bih,
                         const float* __restrict__ bhh, float* __restrict__ W) {
    __shared__ __align__(16) float w0row[F];
    int i = blockIdx.x;
    int j = threadIdx.x;
    w0row[j] = W0[i * F + j];
    __syncthreads();
    float air = 0, aiz = 0, ain = 0, ahr = 0, ahz = 0, ahn = 0;
    const float* ir_p = Wih + (size_t)j * F;
    const float* iz_p = Wih + (size_t)(j + F) * F;
    const float* in_p = Wih + (size_t)(j + 2 * F) * F;
    const float* hr_p = Whh + (size_t)j * F;
    const float* hz_p = Whh + (size_t)(j + F) * F;
    const float* hn_p = Whh + (size_t)(j + 2 * F) * F;
    for (int k = 0; k < F; k += 4) {
        float4 w0 = *(const float4*)&w0row[k];
        float4 a;
        a = *(const float4*)&ir_p[k]; air += w0.x*a.x + w0.y*a.y + w0.z*a.z + w0.w*a.w;
        a = *(const float4*)&iz_p[k]; aiz += w0.x*a.x + w0.y*a.y + w0.z*a.z + w0.w*a.w;
        a = *(const float4*)&in_p[k]; ain += w0.x*a.x + w0.y*a.y + w0.z*a.z + w0.w*a.w;
        a = *(const float4*)&hr_p[k]; ahr += w0.x*a.x + w0.y*a.y + w0.z*a.z + w0.w*a.w;
        a = *(const float4*)&hz_p[k]; ahz += w0.x*a.x + w0.y*a.y + w0.z*a.z + w0.w*a.w;
        a = *(const float4*)&hn_p[k]; ahn += w0.x*a.x + w0.y*a.y + w0.z*a.z + w0.w*a.w;
    }
    air += bih[j];         ahr += bhh[j];
    aiz += bih[j + F];     ahz += bhh[j + F];
    ain += bih[j + 2*F];   ahn += bhh[j + 2*F];
    float r = 1.0f / (1.0f + expf(-(air + ahr)));
    float z = 1.0f / (1.0f + expf(-(aiz + ahz)));
    float n = tanhf(ain + r * ahn);
    W[i * F + j] = (1.0f - z) * n + z * w0row[j];
}

// ---------- K7: xw = x @ W  (fp32, W + x-tile in LDS, 4x4 microtile) ----------
#define TILE_R 32
__global__ __launch_bounds__(256) void k_xw(const float* __restrict__ x,
                                            const float* __restrict__ W,
                                            float* __restrict__ xw, int N) {
    __shared__ __align__(16) float Wl[F * F];        // 64 KB
    __shared__ __align__(16) float Xl[TILE_R * F];   // 16 KB
    int t = threadIdx.x;
    for (int idx = t * 4; idx < F * F; idx += 1024)
        *(float4*)&Wl[idx] = *(const float4*)&W[idx];

    int ct = t & 31, rt = t >> 5;
    int c = ct * 4, r0 = rt * 4;

    for (long long row0 = (long long)blockIdx.x * TILE_R; row0 < N;
         row0 += (long long)gridDim.x * TILE_R) {
        __syncthreads();  // protect Xl (and first-iteration Wl) before rewrite/use
        for (int idx = t * 4; idx < TILE_R * F; idx += 1024) {
            long long gr = row0 + (idx >> 7);
            float4 v = make_float4(0.f, 0.f, 0.f, 0.f);
            if (gr < N) v = *(const float4*)&x[gr * F + (idx & (F - 1))];
            *(float4*)&Xl[idx] = v;
        }
        __syncthreads();

        float acc[4][4] = {};
        for (int k = 0; k < F; k += 4) {
            float4 xv[4], wv[4];
            #pragma unroll
            for (int i = 0; i < 4; ++i) xv[i] = *(const float4*)&Xl[(r0 + i) * F + k];
            #pragma unroll
            for (int kk = 0; kk < 4; ++kk) wv[kk] = *(const float4*)&Wl[(k + kk) * F + c];
            #pragma unroll
            for (int i = 0; i < 4; ++i) {
                acc[i][0] += xv[i].x*wv[0].x + xv[i].y*wv[1].x + xv[i].z*wv[2].x + xv[i].w*wv[3].x;
                acc[i][1] += xv[i].x*wv[0].y + xv[i].y*wv[1].y + xv[i].z*wv[2].y + xv[i].w*wv[3].y;
                acc[i][2] += xv[i].x*wv[0].z + xv[i].y*wv[1].z + xv[i].z*wv[2].z + xv[i].w*wv[3].z;
                acc[i][3] += xv[i].x*wv[0].w + xv[i].y*wv[1].w + xv[i].z*wv[2].w + xv[i].w*wv[3].w;
            }
        }
        #pragma unroll
        for (int i = 0; i < 4; ++i) {
            long long gr = row0 + r0 + i;
            if (gr < N)
                *(float4*)&xw[gr * F + c] = make_float4(acc[i][0], acc[i][1], acc[i][2], acc[i][3]);
        }
    }
}

// ---------- K8: CSR aggregation + self-loop + ReLU + fused final linear ----------
__global__ __launch_bounds__(256) void k_agg(const float* __restrict__ xw,
                                             const int* __restrict__ off,
                                             const int* __restrict__ erow,
                                             const float* __restrict__ ewt,
                                             const float* __restrict__ dinv,
                                             const float* __restrict__ Wlin,
                                             const float* __restrict__ blin,
                                             float* __restrict__ out, int N) {
    int wave = threadIdx.x >> 6;
    int lane = threadIdx.x & 63;
    int c = blockIdx.x * 4 + wave;
    if (c >= N) return;
    // off[] was mutated by scatter: off[c] = end of segment c, off[c-1] = start.
    int start = (c == 0) ? 0 : off[c - 1];
    int end = off[c];
    const float2* xw2 = (const float2*)xw;

    float di = dinv[c];
    float2 h;
    {
        float2 v = xw2[(long long)c * 64 + lane];
        float w = di * di;               // self-loop norm: dinv[c]*1*dinv[c]
        h.x = w * v.x; h.y = w * v.y;
    }
    for (int k = start; k < end; ++k) {
        int r = erow[k];
        float w = ewt[k];
        float2 v = xw2[(long long)r * 64 + lane];
        h.x += w * v.x; h.y += w * v.y;
    }
    h.x = fmaxf(h.x, 0.f);
    h.y = fmaxf(h.y, 0.f);

    const float2* Wl2 = (const float2*)Wlin;
    float p[8];
    #pragma unroll
    for (int t = 0; t < 8; ++t) {
        float2 wv = Wl2[t * 64 + lane];
        p[t] = h.x * wv.x + h.y * wv.y;
    }
    #pragma unroll
    for (int t = 0; t < 8; ++t) {
        #pragma unroll
        for (int s = 1; s < 64; s <<= 1) p[t] += __shfl_xor(p[t], s, 64);
    }
    #pragma unroll
    for (int t = 0; t < 8; ++t)
        if (lane == t) out[(long long)c * 8 + t] = p[t] + blin[t];
}

// ---------- launch ----------
extern "C" void kernel_launch(void* const* d_in, const int* in_sizes, int n_in,
                              void* d_out, int out_size, void* d_ws, size_t ws_size,
                              hipStream_t stream) {
    const float* x    = (const float*)d_in[0];
    const int*   ei   = (const int*)d_in[1];
    const float* ew   = (const float*)d_in[2];
    const float* W0   = (const float*)d_in[3];
    const float* Wih  = (const float*)d_in[4];
    const float* Whh  = (const float*)d_in[5];
    const float* bih  = (const float*)d_in[6];
    const float* bhh  = (const float*)d_in[7];
    const float* Wlin = (const float*)d_in[8];
    const float* blin = (const float*)d_in[9];
    int N = in_sizes[0] / F;   // 50000
    int E = in_sizes[1] / 2;   // 800000
    float* outp = (float*)d_out;

    char* wsb = (char*)d_ws;
    size_t cur = 0;
    auto alloc = [&](size_t sz) -> void* {
        void* p = wsb + cur;
        cur = (cur + sz + 255) & ~(size_t)255;
        return p;
    };
    float* deg  = (float*)alloc((size_t)N * 4);        // becomes dinv in place
    int*   cnt  = (int*)  alloc((size_t)N * 4);
    int*   off  = (int*)  alloc((size_t)(N + 1) * 4);
    int*   flag = (int*)  alloc(256);
    int*   erow = (int*)  alloc((size_t)E * 4);
    float* ewt  = (float*)alloc((size_t)E * 4);
    float* W    = (float*)alloc((size_t)F * F * 4);
    float* xw   = (float*)alloc((size_t)N * F * 4);
    (void)ws_size; (void)n_in; (void)out_size;

    hipLaunchKernelGGL(k_init,    dim3((N + 255) / 256), dim3(256), 0, stream, deg, cnt, flag, ei, N);
    hipLaunchKernelGGL(k_deg,     dim3((E + 255) / 256), dim3(256), 0, stream, ei, ew, deg, cnt, flag, E);
    hipLaunchKernelGGL(k_rsqrt,   dim3((N + 255) / 256), dim3(256), 0, stream, deg, N);
    hipLaunchKernelGGL(k_scan,    dim3(1),               dim3(1024), 0, stream, cnt, off, N);
    hipLaunchKernelGGL(k_scatter, dim3((E + 255) / 256), dim3(256), 0, stream, ei, ew, deg, off, erow, ewt, flag, E);
    hipLaunchKernelGGL(k_evolve,  dim3(F),               dim3(F),   0, stream, W0, Wih, Whh, bih, bhh, W);
    hipLaunchKernelGGL(k_xw,      dim3(512),             dim3(256), 0, stream, x, W, xw, N);
    hipLaunchKernelGGL(k_agg,     dim3((N + 3) / 4),     dim3(256), 0, stream, xw, off, erow, ewt, deg, Wlin, blin, outp, N);
}

// Round 2
// 331.869 us; speedup vs baseline: 1.3248x; 1.3248x over previous
//
#include <hip/hip_runtime.h>
#include <math.h>

#define F 128

// ---------- helpers ----------
__device__ inline int read_idx(const int* ei, long long elem, int i64) {
    return i64 ? (int)((const long long*)ei)[elem] : ei[elem];
}

// ---------- K1: init deg (self-loop weight 1.0), cnt=0, detect index dtype ----------
__global__ void k_init(float* deg, int* cnt, int* flag, const int* ei, int N) {
    int i = blockIdx.x * blockDim.x + threadIdx.x;
    if (i < N) { deg[i] = 1.0f; cnt[i] = 0; }
    if (i == 0) {
        int i64 = 1;
        for (int j = 0; j < 32; ++j) if (ei[2 * j + 1] != 0) { i64 = 0; break; }
        *flag = i64;
    }
}

// ---------- K2: weighted degree by col + per-col edge count ----------
__global__ void k_deg(const int* ei, const float* ew, float* deg, int* cnt,
                      const int* flag, int E) {
    int e = blockIdx.x * blockDim.x + threadIdx.x;
    if (e >= E) return;
    int i64 = *flag;
    int c = read_idx(ei, (long long)E + e, i64);
    atomicAdd(&deg[c], ew[e]);
    atomicAdd(&cnt[c], 1);
}

// ---------- K3a: per-block sums of cnt ----------
__global__ void k_bsum(const int* __restrict__ cnt, int* __restrict__ bsum, int N) {
    __shared__ int s[4];
    int i = blockIdx.x * 256 + threadIdx.x;
    int v = (i < N) ? cnt[i] : 0;
    #pragma unroll
    for (int o = 1; o < 64; o <<= 1) v += __shfl_xor(v, o, 64);
    if ((threadIdx.x & 63) == 0) s[threadIdx.x >> 6] = v;
    __syncthreads();
    if (threadIdx.x == 0) bsum[blockIdx.x] = s[0] + s[1] + s[2] + s[3];
}

// ---------- K3b: exclusive scan of bsum (nb <= a few thousand), one block ----------
__global__ void k_bscan(int* bsum, int nb) {
    __shared__ int sdata[1024];
    int tid = threadIdx.x;
    int run = 0;
    for (int base = 0; base < nb; base += 1024) {
        int i = base + tid;
        int v = (i < nb) ? bsum[i] : 0;
        sdata[tid] = v;
        __syncthreads();
        #pragma unroll
        for (int s = 1; s < 1024; s <<= 1) {
            int add = (tid >= s) ? sdata[tid - s] : 0;
            __syncthreads();
            sdata[tid] += add;
            __syncthreads();
        }
        if (i < nb) bsum[i] = run + sdata[tid] - v;  // exclusive
        run += sdata[1023];
        __syncthreads();
    }
}

// ---------- K3c: off[i] = bsum[blk] + in-block exclusive scan; also dinv=rsqrt(deg) ----------
__global__ void k_offs(const int* __restrict__ cnt, const int* __restrict__ bsum,
                       int* __restrict__ off, float* __restrict__ deg, int N) {
    __shared__ int sdata[256];
    int t = threadIdx.x;
    int i = blockIdx.x * 256 + t;
    int v = (i < N) ? cnt[i] : 0;
    sdata[t] = v;
    __syncthreads();
    #pragma unroll
    for (int s = 1; s < 256; s <<= 1) {
        int add = (t >= s) ? sdata[t - s] : 0;
        __syncthreads();
        sdata[t] += add;
        __syncthreads();
    }
    if (i < N) {
        off[i] = bsum[blockIdx.x] + sdata[t] - v;  // exclusive
        deg[i] = rsqrtf(deg[i]);
    }
}

// ---------- K5: scatter edges into CSR buckets (packed int2); off[] -> segment ends ----------
__global__ void k_scatter(const int* ei, const float* ew, const float* dinv,
                          int* off, int2* ep, const int* flag, int E) {
    int e = blockIdx.x * blockDim.x + threadIdx.x;
    if (e >= E) return;
    int i64 = *flag;
    int r = read_idx(ei, e, i64);
    int c = read_idx(ei, (long long)E + e, i64);
    int pos = atomicAdd(&off[c], 1);
    float wt = dinv[r] * ew[e] * dinv[c];
    ep[pos] = make_int2(r, __float_as_int(wt));
}

// ---------- K6: GRU weight evolution ----------
__global__ void k_evolve(const float* __restrict__ W0, const float* __restrict__ Wih,
                         const float* __restrict__ Whh, const float* __restrict__ bih,
                         const float* __restrict__ bhh, float* __restrict__ W) {
    __shared__ __align__(16) float w0row[F];
    int i = blockIdx.x;
    int j = threadIdx.x;
    w0row[j] = W0[i * F + j];
    __syncthreads();
    float air = 0, aiz = 0, ain = 0, ahr = 0, ahz = 0, ahn = 0;
    const float* ir_p = Wih + (size_t)j * F;
    const float* iz_p = Wih + (size_t)(j + F) * F;
    const float* in_p = Wih + (size_t)(j + 2 * F) * F;
    const float* hr_p = Whh + (size_t)j * F;
    const float* hz_p = Whh + (size_t)(j + F) * F;
    const float* hn_p = Whh + (size_t)(j + 2 * F) * F;
    for (int k = 0; k < F; k += 4) {
        float4 w0 = *(const float4*)&w0row[k];
        float4 a;
        a = *(const float4*)&ir_p[k]; air += w0.x*a.x + w0.y*a.y + w0.z*a.z + w0.w*a.w;
        a = *(const float4*)&iz_p[k]; aiz += w0.x*a.x + w0.y*a.y + w0.z*a.z + w0.w*a.w;
        a = *(const float4*)&in_p[k]; ain += w0.x*a.x + w0.y*a.y + w0.z*a.z + w0.w*a.w;
        a = *(const float4*)&hr_p[k]; ahr += w0.x*a.x + w0.y*a.y + w0.z*a.z + w0.w*a.w;
        a = *(const float4*)&hz_p[k]; ahz += w0.x*a.x + w0.y*a.y + w0.z*a.z + w0.w*a.w;
        a = *(const float4*)&hn_p[k]; ahn += w0.x*a.x + w0.y*a.y + w0.z*a.z + w0.w*a.w;
    }
    air += bih[j];         ahr += bhh[j];
    aiz += bih[j + F];     ahz += bhh[j + F];
    ain += bih[j + 2*F];   ahn += bhh[j + 2*F];
    float r = 1.0f / (1.0f + expf(-(air + ahr)));
    float z = 1.0f / (1.0f + expf(-(aiz + ahz)));
    float n = tanhf(ain + r * ahn);
    W[i * F + j] = (1.0f - z) * n + z * w0row[j];
}

// ---------- K7: xw = x @ W ----------
#define TILE_R 32
__global__ __launch_bounds__(256) void k_xw(const float* __restrict__ x,
                                            const float* __restrict__ W,
                                            float* __restrict__ xw, int N) {
    __shared__ __align__(16) float Wl[F * F];
    __shared__ __align__(16) float Xl[TILE_R * F];
    int t = threadIdx.x;
    for (int idx = t * 4; idx < F * F; idx += 1024)
        *(float4*)&Wl[idx] = *(const float4*)&W[idx];

    int ct = t & 31, rt = t >> 5;
    int c = ct * 4, r0 = rt * 4;

    for (long long row0 = (long long)blockIdx.x * TILE_R; row0 < N;
         row0 += (long long)gridDim.x * TILE_R) {
        __syncthreads();
        for (int idx = t * 4; idx < TILE_R * F; idx += 1024) {
            long long gr = row0 + (idx >> 7);
            float4 v = make_float4(0.f, 0.f, 0.f, 0.f);
            if (gr < N) v = *(const float4*)&x[gr * F + (idx & (F - 1))];
            *(float4*)&Xl[idx] = v;
        }
        __syncthreads();

        float acc[4][4] = {};
        for (int k = 0; k < F; k += 4) {
            float4 xv[4], wv[4];
            #pragma unroll
            for (int i = 0; i < 4; ++i) xv[i] = *(const float4*)&Xl[(r0 + i) * F + k];
            #pragma unroll
            for (int kk = 0; kk < 4; ++kk) wv[kk] = *(const float4*)&Wl[(k + kk) * F + c];
            #pragma unroll
            for (int i = 0; i < 4; ++i) {
                acc[i][0] += xv[i].x*wv[0].x + xv[i].y*wv[1].x + xv[i].z*wv[2].x + xv[i].w*wv[3].x;
                acc[i][1] += xv[i].x*wv[0].y + xv[i].y*wv[1].y + xv[i].z*wv[2].y + xv[i].w*wv[3].y;
                acc[i][2] += xv[i].x*wv[0].z + xv[i].y*wv[1].z + xv[i].z*wv[2].z + xv[i].w*wv[3].z;
                acc[i][3] += xv[i].x*wv[0].w + xv[i].y*wv[1].w + xv[i].z*wv[2].w + xv[i].w*wv[3].w;
            }
        }
        #pragma unroll
        for (int i = 0; i < 4; ++i) {
            long long gr = row0 + r0 + i;
            if (gr < N)
                *(float4*)&xw[gr * F + c] = make_float4(acc[i][0], acc[i][1], acc[i][2], acc[i][3]);
        }
    }
}

// ---------- K8: CSR aggregation + self-loop + ReLU + fused final linear ----------
__global__ __launch_bounds__(256) void k_agg(const float* __restrict__ xw,
                                             const int* __restrict__ off,
                                             const int2* __restrict__ ep,
                                             const float* __restrict__ dinv,
                                             const float* __restrict__ Wlin,
                                             const float* __restrict__ blin,
                                             float* __restrict__ out, int N) {
    int wave = threadIdx.x >> 6;
    int lane = threadIdx.x & 63;
    int c = blockIdx.x * 4 + wave;
    if (c >= N) return;
    int start = (c == 0) ? 0 : off[c - 1];
    int end = off[c];
    const float2* xw2 = (const float2*)xw;

    float di = dinv[c];
    float2 h0, h1 = make_float2(0.f, 0.f), h2 = make_float2(0.f, 0.f), h3 = make_float2(0.f, 0.f);
    {
        float2 v = xw2[(long long)c * 64 + lane];
        float w = di * di;
        h0.x = w * v.x; h0.y = w * v.y;
    }
    int k = start;
    // 4-way unrolled gather: 4 independent load chains for MLP
    for (; k + 4 <= end; k += 4) {
        int2 e0 = ep[k], e1 = ep[k + 1], e2 = ep[k + 2], e3 = ep[k + 3];
        float2 v0 = xw2[(long long)e0.x * 64 + lane];
        float2 v1 = xw2[(long long)e1.x * 64 + lane];
        float2 v2 = xw2[(long long)e2.x * 64 + lane];
        float2 v3 = xw2[(long long)e3.x * 64 + lane];
        float w0 = __int_as_float(e0.y), w1 = __int_as_float(e1.y);
        float w2 = __int_as_float(e2.y), w3 = __int_as_float(e3.y);
        h0.x += w0 * v0.x; h0.y += w0 * v0.y;
        h1.x += w1 * v1.x; h1.y += w1 * v1.y;
        h2.x += w2 * v2.x; h2.y += w2 * v2.y;
        h3.x += w3 * v3.x; h3.y += w3 * v3.y;
    }
    for (; k < end; ++k) {
        int2 e0 = ep[k];
        float2 v0 = xw2[(long long)e0.x * 64 + lane];
        float w0 = __int_as_float(e0.y);
        h0.x += w0 * v0.x; h0.y += w0 * v0.y;
    }
    float2 h;
    h.x = (h0.x + h1.x) + (h2.x + h3.x);
    h.y = (h0.y + h1.y) + (h2.y + h3.y);
    h.x = fmaxf(h.x, 0.f);
    h.y = fmaxf(h.y, 0.f);

    const float2* Wl2 = (const float2*)Wlin;
    float p[8];
    #pragma unroll
    for (int t = 0; t < 8; ++t) {
        float2 wv = Wl2[t * 64 + lane];
        p[t] = h.x * wv.x + h.y * wv.y;
    }
    #pragma unroll
    for (int t = 0; t < 8; ++t) {
        #pragma unroll
        for (int s = 1; s < 64; s <<= 1) p[t] += __shfl_xor(p[t], s, 64);
    }
    #pragma unroll
    for (int t = 0; t < 8; ++t)
        if (lane == t) out[(long long)c * 8 + t] = p[t] + blin[t];
}

// ---------- launch ----------
extern "C" void kernel_launch(void* const* d_in, const int* in_sizes, int n_in,
                              void* d_out, int out_size, void* d_ws, size_t ws_size,
                              hipStream_t stream) {
    const float* x    = (const float*)d_in[0];
    const int*   ei   = (const int*)d_in[1];
    const float* ew   = (const float*)d_in[2];
    const float* W0   = (const float*)d_in[3];
    const float* Wih  = (const float*)d_in[4];
    const float* Whh  = (const float*)d_in[5];
    const float* bih  = (const float*)d_in[6];
    const float* bhh  = (const float*)d_in[7];
    const float* Wlin = (const float*)d_in[8];
    const float* blin = (const float*)d_in[9];
    int N = in_sizes[0] / F;   // 50000
    int E = in_sizes[1] / 2;   // 800000
    float* outp = (float*)d_out;

    int nblk = (N + 255) / 256;

    char* wsb = (char*)d_ws;
    size_t cur = 0;
    auto alloc = [&](size_t sz) -> void* {
        void* p = wsb + cur;
        cur = (cur + sz + 255) & ~(size_t)255;
        return p;
    };
    float* deg  = (float*)alloc((size_t)N * 4);        // becomes dinv in place
    int*   cnt  = (int*)  alloc((size_t)N * 4);
    int*   off  = (int*)  alloc((size_t)(N + 1) * 4);
    int*   bsum = (int*)  alloc((size_t)nblk * 4);
    int*   flag = (int*)  alloc(256);
    int2*  ep   = (int2*) alloc((size_t)E * 8);
    float* W    = (float*)alloc((size_t)F * F * 4);
    float* xw   = (float*)alloc((size_t)N * F * 4);
    (void)ws_size; (void)n_in; (void)out_size;

    hipLaunchKernelGGL(k_init,    dim3(nblk),            dim3(256),  0, stream, deg, cnt, flag, ei, N);
    hipLaunchKernelGGL(k_deg,     dim3((E + 255) / 256), dim3(256),  0, stream, ei, ew, deg, cnt, flag, E);
    hipLaunchKernelGGL(k_bsum,    dim3(nblk),            dim3(256),  0, stream, cnt, bsum, N);
    hipLaunchKernelGGL(k_bscan,   dim3(1),               dim3(1024), 0, stream, bsum, nblk);
    hipLaunchKernelGGL(k_offs,    dim3(nblk),            dim3(256),  0, stream, cnt, bsum, off, deg, N);
    hipLaunchKernelGGL(k_scatter, dim3((E + 255) / 256), dim3(256),  0, stream, ei, ew, deg, off, ep, flag, E);
    hipLaunchKernelGGL(k_evolve,  dim3(F),               dim3(F),    0, stream, W0, Wih, Whh, bih, bhh, W);
    hipLaunchKernelGGL(k_xw,      dim3(512),             dim3(256),  0, stream, x, W, xw, N);
    hipLaunchKernelGGL(k_agg,     dim3((N + 3) / 4),     dim3(256),  0, stream, xw, off, ep, deg, Wlin, blin, outp, N);
}

// Round 3
// 279.940 us; speedup vs baseline: 1.5705x; 1.1855x over previous
//
#include <hip/hip_runtime.h>
#include <math.h>

#define F 128
#define FIX_SCALE 16777216.0f          // 2^24
#define FIX_INV   (1.0f / 16777216.0f)
#define CNT_SHIFT 40
#define DEG_MASK  ((1ULL << 40) - 1)

// ---------- helpers ----------
__device__ inline int read_idx(const int* ei, long long elem, int i64) {
    return i64 ? (int)((const long long*)ei)[elem] : ei[elem];
}

// ---------- K1: zero packed counters, detect index dtype ----------
__global__ void k_init(unsigned long long* packed, int* flag, const int* ei, int N) {
    int i = blockIdx.x * blockDim.x + threadIdx.x;
    if (i < N) packed[i] = 0ULL;
    if (i == 0) {
        int i64 = 1;
        for (int j = 0; j < 32; ++j) if (ei[2 * j + 1] != 0) { i64 = 0; break; }
        *flag = i64;
    }
}

// ---------- K2: ONE packed 64-bit atomic per edge: count + fixed-point deg; pos = old count ----------
__global__ void k_count(const int* ei, const float* ew, unsigned long long* packed,
                        int* pos, const int* flag, int E) {
    int e = blockIdx.x * blockDim.x + threadIdx.x;
    if (e >= E) return;
    int i64 = *flag;
    int c = read_idx(ei, (long long)E + e, i64);
    unsigned long long u = (1ULL << CNT_SHIFT) |
                           (unsigned long long)(ew[e] * FIX_SCALE + 0.5f);
    unsigned long long old = atomicAdd(&packed[c], u);
    pos[e] = (int)(old >> CNT_SHIFT);
}

// ---------- K3a: per-block sums of cnt (from packed high bits) ----------
__global__ void k_bsum(const unsigned long long* __restrict__ packed,
                       int* __restrict__ bsum, int N) {
    __shared__ int s[4];
    int i = blockIdx.x * 256 + threadIdx.x;
    int v = (i < N) ? (int)(packed[i] >> CNT_SHIFT) : 0;
    #pragma unroll
    for (int o = 1; o < 64; o <<= 1) v += __shfl_xor(v, o, 64);
    if ((threadIdx.x & 63) == 0) s[threadIdx.x >> 6] = v;
    __syncthreads();
    if (threadIdx.x == 0) bsum[blockIdx.x] = s[0] + s[1] + s[2] + s[3];
}

// ---------- K3b: exclusive scan of bsum (nblk ~ 196), one block ----------
__global__ void k_bscan(int* bsum, int nb) {
    __shared__ int sdata[1024];
    int tid = threadIdx.x;
    int run = 0;
    for (int base = 0; base < nb; base += 1024) {
        int i = base + tid;
        int v = (i < nb) ? bsum[i] : 0;
        sdata[tid] = v;
        __syncthreads();
        #pragma unroll
        for (int s = 1; s < 1024; s <<= 1) {
            int add = (tid >= s) ? sdata[tid - s] : 0;
            __syncthreads();
            sdata[tid] += add;
            __syncthreads();
        }
        if (i < nb) bsum[i] = run + sdata[tid] - v;  // exclusive
        run += sdata[1023];
        __syncthreads();
    }
}

// ---------- K3c: off = exclusive CSR offsets (immutable); dinv = rsqrt(1 + deg) ----------
__global__ void k_offs(const unsigned long long* __restrict__ packed,
                       const int* __restrict__ bsum,
                       int* __restrict__ off, float* __restrict__ dinv, int N, int E) {
    __shared__ int sdata[256];
    int t = threadIdx.x;
    int i = blockIdx.x * 256 + t;
    unsigned long long p = (i < N) ? packed[i] : 0ULL;
    int v = (int)(p >> CNT_SHIFT);
    sdata[t] = v;
    __syncthreads();
    #pragma unroll
    for (int s = 1; s < 256; s <<= 1) {
        int add = (t >= s) ? sdata[t - s] : 0;
        __syncthreads();
        sdata[t] += add;
        __syncthreads();
    }
    if (i < N) {
        off[i] = bsum[blockIdx.x] + sdata[t] - v;  // exclusive
        float deg = 1.0f + (float)(p & DEG_MASK) * FIX_INV;  // +1 self-loop
        dinv[i] = rsqrtf(deg);
        if (i == N - 1) off[N] = E;
    }
}

// ---------- K5: atomic-free placement into CSR (packed int2 = row, ewt) ----------
__global__ void k_place(const int* ei, const float* ew, const float* __restrict__ dinv,
                        const int* __restrict__ off, const int* __restrict__ pos,
                        int2* ep, const int* flag, int E) {
    int e = blockIdx.x * blockDim.x + threadIdx.x;
    if (e >= E) return;
    int i64 = *flag;
    int r = read_idx(ei, e, i64);
    int c = read_idx(ei, (long long)E + e, i64);
    float wt = dinv[r] * ew[e] * dinv[c];
    ep[off[c] + pos[e]] = make_int2(r, __float_as_int(wt));
}

// ---------- K6: GRU weight evolution ----------
__global__ void k_evolve(const float* __restrict__ W0, const float* __restrict__ Wih,
                         const float* __restrict__ Whh, const float* __restrict__ bih,
                         const float* __restrict__ bhh, float* __restrict__ W) {
    __shared__ __align__(16) float w0row[F];
    int i = blockIdx.x;
    int j = threadIdx.x;
    w0row[j] = W0[i * F + j];
    __syncthreads();
    float air = 0, aiz = 0, ain = 0, ahr = 0, ahz = 0, ahn = 0;
    const float* ir_p = Wih + (size_t)j * F;
    const float* iz_p = Wih + (size_t)(j + F) * F;
    const float* in_p = Wih + (size_t)(j + 2 * F) * F;
    const float* hr_p = Whh + (size_t)j * F;
    const float* hz_p = Whh + (size_t)(j + F) * F;
    const float* hn_p = Whh + (size_t)(j + 2 * F) * F;
    for (int k = 0; k < F; k += 4) {
        float4 w0 = *(const float4*)&w0row[k];
        float4 a;
        a = *(const float4*)&ir_p[k]; air += w0.x*a.x + w0.y*a.y + w0.z*a.z + w0.w*a.w;
        a = *(const float4*)&iz_p[k]; aiz += w0.x*a.x + w0.y*a.y + w0.z*a.z + w0.w*a.w;
        a = *(const float4*)&in_p[k]; ain += w0.x*a.x + w0.y*a.y + w0.z*a.z + w0.w*a.w;
        a = *(const float4*)&hr_p[k]; ahr += w0.x*a.x + w0.y*a.y + w0.z*a.z + w0.w*a.w;
        a = *(const float4*)&hz_p[k]; ahz += w0.x*a.x + w0.y*a.y + w0.z*a.z + w0.w*a.w;
        a = *(const float4*)&hn_p[k]; ahn += w0.x*a.x + w0.y*a.y + w0.z*a.z + w0.w*a.w;
    }
    air += bih[j];         ahr += bhh[j];
    aiz += bih[j + F];     ahz += bhh[j + F];
    ain += bih[j + 2*F];   ahn += bhh[j + 2*F];
    float r = 1.0f / (1.0f + expf(-(air + ahr)));
    float z = 1.0f / (1.0f + expf(-(aiz + ahz)));
    float n = tanhf(ain + r * ahn);
    W[i * F + j] = (1.0f - z) * n + z * w0row[j];
}

// ---------- K7: xw = x @ W ----------
#define TILE_R 32
__global__ __launch_bounds__(256) void k_xw(const float* __restrict__ x,
                                            const float* __restrict__ W,
                                            float* __restrict__ xw, int N) {
    __shared__ __align__(16) float Wl[F * F];
    __shared__ __align__(16) float Xl[TILE_R * F];
    int t = threadIdx.x;
    for (int idx = t * 4; idx < F * F; idx += 1024)
        *(float4*)&Wl[idx] = *(const float4*)&W[idx];

    int ct = t & 31, rt = t >> 5;
    int c = ct * 4, r0 = rt * 4;

    for (long long row0 = (long long)blockIdx.x * TILE_R; row0 < N;
         row0 += (long long)gridDim.x * TILE_R) {
        __syncthreads();
        for (int idx = t * 4; idx < TILE_R * F; idx += 1024) {
            long long gr = row0 + (idx >> 7);
            float4 v = make_float4(0.f, 0.f, 0.f, 0.f);
            if (gr < N) v = *(const float4*)&x[gr * F + (idx & (F - 1))];
            *(float4*)&Xl[idx] = v;
        }
        __syncthreads();

        float acc[4][4] = {};
        for (int k = 0; k < F; k += 4) {
            float4 xv[4], wv[4];
            #pragma unroll
            for (int i = 0; i < 4; ++i) xv[i] = *(const float4*)&Xl[(r0 + i) * F + k];
            #pragma unroll
            for (int kk = 0; kk < 4; ++kk) wv[kk] = *(const float4*)&Wl[(k + kk) * F + c];
            #pragma unroll
            for (int i = 0; i < 4; ++i) {
                acc[i][0] += xv[i].x*wv[0].x + xv[i].y*wv[1].x + xv[i].z*wv[2].x + xv[i].w*wv[3].x;
                acc[i][1] += xv[i].x*wv[0].y + xv[i].y*wv[1].y + xv[i].z*wv[2].y + xv[i].w*wv[3].y;
                acc[i][2] += xv[i].x*wv[0].z + xv[i].y*wv[1].z + xv[i].z*wv[2].z + xv[i].w*wv[3].z;
                acc[i][3] += xv[i].x*wv[0].w + xv[i].y*wv[1].w + xv[i].z*wv[2].w + xv[i].w*wv[3].w;
            }
        }
        #pragma unroll
        for (int i = 0; i < 4; ++i) {
            long long gr = row0 + r0 + i;
            if (gr < N)
                *(float4*)&xw[gr * F + c] = make_float4(acc[i][0], acc[i][1], acc[i][2], acc[i][3]);
        }
    }
}

// ---------- K8: CSR aggregation + self-loop + ReLU + fused final linear ----------
__global__ __launch_bounds__(256) void k_agg(const float* __restrict__ xw,
                                             const int* __restrict__ off,
                                             const int2* __restrict__ ep,
                                             const float* __restrict__ dinv,
                                             const float* __restrict__ Wlin,
                                             const float* __restrict__ blin,
                                             float* __restrict__ out, int N) {
    int wave = threadIdx.x >> 6;
    int lane = threadIdx.x & 63;
    int c = blockIdx.x * 4 + wave;
    if (c >= N) return;
    int start = off[c];
    int end = off[c + 1];
    const float2* xw2 = (const float2*)xw;

    float di = dinv[c];
    float2 acc[8];
    #pragma unroll
    for (int u = 0; u < 8; ++u) acc[u] = make_float2(0.f, 0.f);
    {
        float2 v = xw2[(long long)c * 64 + lane];
        float w = di * di;                  // self-loop norm
        acc[0].x = w * v.x; acc[0].y = w * v.y;
    }
    // 8-wide blocked gather with wave-uniform guards: all loads in a block
    // are independent (deep MLP), no serial remainder chain.
    for (int k = start; k < end; k += 8) {
        int2 e[8];
        #pragma unroll
        for (int u = 0; u < 8; ++u)
            if (k + u < end) e[u] = ep[k + u];
        #pragma unroll
        for (int u = 0; u < 8; ++u) {
            if (k + u < end) {
                float2 v = xw2[(long long)e[u].x * 64 + lane];
                float w = __int_as_float(e[u].y);
                acc[u].x += w * v.x; acc[u].y += w * v.y;
            }
        }
    }
    float2 h;
    h.x = ((acc[0].x + acc[1].x) + (acc[2].x + acc[3].x)) +
          ((acc[4].x + acc[5].x) + (acc[6].x + acc[7].x));
    h.y = ((acc[0].y + acc[1].y) + (acc[2].y + acc[3].y)) +
          ((acc[4].y + acc[5].y) + (acc[6].y + acc[7].y));
    h.x = fmaxf(h.x, 0.f);
    h.y = fmaxf(h.y, 0.f);

    const float2* Wl2 = (const float2*)Wlin;
    float p[8];
    #pragma unroll
    for (int t = 0; t < 8; ++t) {
        float2 wv = Wl2[t * 64 + lane];
        p[t] = h.x * wv.x + h.y * wv.y;
    }
    #pragma unroll
    for (int t = 0; t < 8; ++t) {
        #pragma unroll
        for (int s = 1; s < 64; s <<= 1) p[t] += __shfl_xor(p[t], s, 64);
    }
    #pragma unroll
    for (int t = 0; t < 8; ++t)
        if (lane == t) out[(long long)c * 8 + t] = p[t] + blin[t];
}

// ---------- launch ----------
extern "C" void kernel_launch(void* const* d_in, const int* in_sizes, int n_in,
                              void* d_out, int out_size, void* d_ws, size_t ws_size,
                              hipStream_t stream) {
    const float* x    = (const float*)d_in[0];
    const int*   ei   = (const int*)d_in[1];
    const float* ew   = (const float*)d_in[2];
    const float* W0   = (const float*)d_in[3];
    const float* Wih  = (const float*)d_in[4];
    const float* Whh  = (const float*)d_in[5];
    const float* bih  = (const float*)d_in[6];
    const float* bhh  = (const float*)d_in[7];
    const float* Wlin = (const float*)d_in[8];
    const float* blin = (const float*)d_in[9];
    int N = in_sizes[0] / F;   // 50000
    int E = in_sizes[1] / 2;   // 800000
    float* outp = (float*)d_out;

    int nblk = (N + 255) / 256;

    char* wsb = (char*)d_ws;
    size_t cur = 0;
    auto alloc = [&](size_t sz) -> void* {
        void* p = wsb + cur;
        cur = (cur + sz + 255) & ~(size_t)255;
        return p;
    };
    unsigned long long* packed = (unsigned long long*)alloc((size_t)N * 8);
    float* dinv = (float*)alloc((size_t)N * 4);
    int*   off  = (int*)  alloc((size_t)(N + 1) * 4);
    int*   bsum = (int*)  alloc((size_t)nblk * 4);
    int*   flag = (int*)  alloc(256);
    int*   pos  = (int*)  alloc((size_t)E * 4);
    int2*  ep   = (int2*) alloc((size_t)E * 8);
    float* W    = (float*)alloc((size_t)F * F * 4);
    float* xw   = (float*)alloc((size_t)N * F * 4);
    (void)ws_size; (void)n_in; (void)out_size;

    hipLaunchKernelGGL(k_init,   dim3(nblk),            dim3(256),  0, stream, packed, flag, ei, N);
    hipLaunchKernelGGL(k_count,  dim3((E + 255) / 256), dim3(256),  0, stream, ei, ew, packed, pos, flag, E);
    hipLaunchKernelGGL(k_bsum,   dim3(nblk),            dim3(256),  0, stream, packed, bsum, N);
    hipLaunchKernelGGL(k_bscan,  dim3(1),               dim3(1024), 0, stream, bsum, nblk);
    hipLaunchKernelGGL(k_offs,   dim3(nblk),            dim3(256),  0, stream, packed, bsum, off, dinv, N, E);
    hipLaunchKernelGGL(k_place,  dim3((E + 255) / 256), dim3(256),  0, stream, ei, ew, dinv, off, pos, ep, flag, E);
    hipLaunchKernelGGL(k_evolve, dim3(F),               dim3(F),    0, stream, W0, Wih, Whh, bih, bhh, W);
    hipLaunchKernelGGL(k_xw,     dim3(512),             dim3(256),  0, stream, x, W, xw, N);
    hipLaunchKernelGGL(k_agg,    dim3((N + 3) / 4),     dim3(256),  0, stream, xw, off, ep, dinv, Wlin, blin, outp, N);
}

// Round 4
// 274.516 us; speedup vs baseline: 1.6015x; 1.0198x over previous
//
#include <hip/hip_runtime.h>
#include <math.h>

#define F 128
#define FIX_SCALE 16777216.0f          // 2^24
#define FIX_INV   (1.0f / 16777216.0f)
#define CNT_SHIFT 40
#define DEG_MASK  ((1ULL << 40) - 1)

// ---------- helpers ----------
__device__ inline int read_idx(const int* ei, long long elem, int i64) {
    return i64 ? (int)((const long long*)ei)[elem] : ei[elem];
}
__device__ inline unsigned int f2bf_rn(float f) {   // fp32 -> bf16 bits, round-nearest-even
    unsigned int b = __float_as_uint(f);
    return (b + 0x7FFFu + ((b >> 16) & 1u)) >> 16;
}

// ---------- K1: zero packed counters, detect index dtype ----------
__global__ void k_init(unsigned long long* packed, int* flag, const int* ei, int N) {
    int i = blockIdx.x * blockDim.x + threadIdx.x;
    if (i < N) packed[i] = 0ULL;
    if (i == 0) {
        int i64 = 1;
        for (int j = 0; j < 32; ++j) if (ei[2 * j + 1] != 0) { i64 = 0; break; }
        *flag = i64;
    }
}

// ---------- K2: ONE packed 64-bit atomic per edge: count + fixed-point deg; pos = old count ----------
__global__ void k_count(const int* ei, const float* ew, unsigned long long* packed,
                        int* pos, const int* flag, int E) {
    int e = blockIdx.x * blockDim.x + threadIdx.x;
    if (e >= E) return;
    int i64 = *flag;
    int c = read_idx(ei, (long long)E + e, i64);
    unsigned long long u = (1ULL << CNT_SHIFT) |
                           (unsigned long long)(ew[e] * FIX_SCALE + 0.5f);
    unsigned long long old = atomicAdd(&packed[c], u);
    pos[e] = (int)(old >> CNT_SHIFT);
}

// ---------- K3a: per-block sums of cnt ----------
__global__ void k_bsum(const unsigned long long* __restrict__ packed,
                       int* __restrict__ bsum, int N) {
    __shared__ int s[4];
    int i = blockIdx.x * 256 + threadIdx.x;
    int v = (i < N) ? (int)(packed[i] >> CNT_SHIFT) : 0;
    #pragma unroll
    for (int o = 1; o < 64; o <<= 1) v += __shfl_xor(v, o, 64);
    if ((threadIdx.x & 63) == 0) s[threadIdx.x >> 6] = v;
    __syncthreads();
    if (threadIdx.x == 0) bsum[blockIdx.x] = s[0] + s[1] + s[2] + s[3];
}

// ---------- K3b: exclusive scan of bsum (nblk ~ 196), one block ----------
__global__ void k_bscan(int* bsum, int nb) {
    __shared__ int sdata[1024];
    int tid = threadIdx.x;
    int run = 0;
    for (int base = 0; base < nb; base += 1024) {
        int i = base + tid;
        int v = (i < nb) ? bsum[i] : 0;
        sdata[tid] = v;
        __syncthreads();
        #pragma unroll
        for (int s = 1; s < 1024; s <<= 1) {
            int add = (tid >= s) ? sdata[tid - s] : 0;
            __syncthreads();
            sdata[tid] += add;
            __syncthreads();
        }
        if (i < nb) bsum[i] = run + sdata[tid] - v;  // exclusive
        run += sdata[1023];
        __syncthreads();
    }
}

// ---------- K3c: off = exclusive CSR offsets; dinv = rsqrt(1 + deg) ----------
__global__ void k_offs(const unsigned long long* __restrict__ packed,
                       const int* __restrict__ bsum,
                       int* __restrict__ off, float* __restrict__ dinv, int N, int E) {
    __shared__ int sdata[256];
    int t = threadIdx.x;
    int i = blockIdx.x * 256 + t;
    unsigned long long p = (i < N) ? packed[i] : 0ULL;
    int v = (int)(p >> CNT_SHIFT);
    sdata[t] = v;
    __syncthreads();
    #pragma unroll
    for (int s = 1; s < 256; s <<= 1) {
        int add = (t >= s) ? sdata[t - s] : 0;
        __syncthreads();
        sdata[t] += add;
        __syncthreads();
    }
    if (i < N) {
        off[i] = bsum[blockIdx.x] + sdata[t] - v;  // exclusive
        float deg = 1.0f + (float)(p & DEG_MASK) * FIX_INV;  // +1 self-loop
        dinv[i] = rsqrtf(deg);
        if (i == N - 1) off[N] = E;
    }
}

// ---------- K5: atomic-free, gather-free placement: ep = (row, raw ew) ----------
__global__ void k_place(const int* ei, const float* ew,
                        const int* __restrict__ off, const int* __restrict__ pos,
                        int2* ep, const int* flag, int E) {
    int e = blockIdx.x * blockDim.x + threadIdx.x;
    if (e >= E) return;
    int i64 = *flag;
    int r = read_idx(ei, e, i64);
    int c = read_idx(ei, (long long)E + e, i64);
    ep[off[c] + pos[e]] = make_int2(r, __float_as_int(ew[e]));
}

// ---------- K6: GRU weight evolution ----------
__global__ void k_evolve(const float* __restrict__ W0, const float* __restrict__ Wih,
                         const float* __restrict__ Whh, const float* __restrict__ bih,
                         const float* __restrict__ bhh, float* __restrict__ W) {
    __shared__ __align__(16) float w0row[F];
    int i = blockIdx.x;
    int j = threadIdx.x;
    w0row[j] = W0[i * F + j];
    __syncthreads();
    float air = 0, aiz = 0, ain = 0, ahr = 0, ahz = 0, ahn = 0;
    const float* ir_p = Wih + (size_t)j * F;
    const float* iz_p = Wih + (size_t)(j + F) * F;
    const float* in_p = Wih + (size_t)(j + 2 * F) * F;
    const float* hr_p = Whh + (size_t)j * F;
    const float* hz_p = Whh + (size_t)(j + F) * F;
    const float* hn_p = Whh + (size_t)(j + 2 * F) * F;
    for (int k = 0; k < F; k += 4) {
        float4 w0 = *(const float4*)&w0row[k];
        float4 a;
        a = *(const float4*)&ir_p[k]; air += w0.x*a.x + w0.y*a.y + w0.z*a.z + w0.w*a.w;
        a = *(const float4*)&iz_p[k]; aiz += w0.x*a.x + w0.y*a.y + w0.z*a.z + w0.w*a.w;
        a = *(const float4*)&in_p[k]; ain += w0.x*a.x + w0.y*a.y + w0.z*a.z + w0.w*a.w;
        a = *(const float4*)&hr_p[k]; ahr += w0.x*a.x + w0.y*a.y + w0.z*a.z + w0.w*a.w;
        a = *(const float4*)&hz_p[k]; ahz += w0.x*a.x + w0.y*a.y + w0.z*a.z + w0.w*a.w;
        a = *(const float4*)&hn_p[k]; ahn += w0.x*a.x + w0.y*a.y + w0.z*a.z + w0.w*a.w;
    }
    air += bih[j];         ahr += bhh[j];
    aiz += bih[j + F];     ahz += bhh[j + F];
    ain += bih[j + 2*F];   ahn += bhh[j + 2*F];
    float r = 1.0f / (1.0f + expf(-(air + ahr)));
    float z = 1.0f / (1.0f + expf(-(aiz + ahz)));
    float n = tanhf(ain + r * ahn);
    W[i * F + j] = (1.0f - z) * n + z * w0row[j];
}

// ---------- K7: xw = dinv[row] * (x @ W), stored as bf16 ----------
#define TILE_R 32
__global__ __launch_bounds__(256) void k_xw(const float* __restrict__ x,
                                            const float* __restrict__ W,
                                            const float* __restrict__ dinv,
                                            unsigned int* __restrict__ xwb, int N) {
    __shared__ __align__(16) float Wl[F * F];
    __shared__ __align__(16) float Xl[TILE_R * F];
    int t = threadIdx.x;
    for (int idx = t * 4; idx < F * F; idx += 1024)
        *(float4*)&Wl[idx] = *(const float4*)&W[idx];

    int ct = t & 31, rt = t >> 5;
    int c = ct * 4, r0 = rt * 4;

    for (long long row0 = (long long)blockIdx.x * TILE_R; row0 < N;
         row0 += (long long)gridDim.x * TILE_R) {
        __syncthreads();
        for (int idx = t * 4; idx < TILE_R * F; idx += 1024) {
            long long gr = row0 + (idx >> 7);
            float4 v = make_float4(0.f, 0.f, 0.f, 0.f);
            if (gr < N) v = *(const float4*)&x[gr * F + (idx & (F - 1))];
            *(float4*)&Xl[idx] = v;
        }
        __syncthreads();

        float acc[4][4] = {};
        for (int k = 0; k < F; k += 4) {
            float4 xv[4], wv[4];
            #pragma unroll
            for (int i = 0; i < 4; ++i) xv[i] = *(const float4*)&Xl[(r0 + i) * F + k];
            #pragma unroll
            for (int kk = 0; kk < 4; ++kk) wv[kk] = *(const float4*)&Wl[(k + kk) * F + c];
            #pragma unroll
            for (int i = 0; i < 4; ++i) {
                acc[i][0] += xv[i].x*wv[0].x + xv[i].y*wv[1].x + xv[i].z*wv[2].x + xv[i].w*wv[3].x;
                acc[i][1] += xv[i].x*wv[0].y + xv[i].y*wv[1].y + xv[i].z*wv[2].y + xv[i].w*wv[3].y;
                acc[i][2] += xv[i].x*wv[0].z + xv[i].y*wv[1].z + xv[i].z*wv[2].z + xv[i].w*wv[3].z;
                acc[i][3] += xv[i].x*wv[0].w + xv[i].y*wv[1].w + xv[i].z*wv[2].w + xv[i].w*wv[3].w;
            }
        }
        #pragma unroll
        for (int i = 0; i < 4; ++i) {
            long long gr = row0 + r0 + i;
            if (gr < N) {
                float di = dinv[gr];
                unsigned int p0 = f2bf_rn(di * acc[i][0]) | (f2bf_rn(di * acc[i][1]) << 16);
                unsigned int p1 = f2bf_rn(di * acc[i][2]) | (f2bf_rn(di * acc[i][3]) << 16);
                // xwb row stride = 64 uints (128 bf16)
                *(uint2*)&xwb[gr * 64 + (c >> 1)] = make_uint2(p0, p1);
            }
        }
    }
}

// ---------- K8: CSR aggregation (bf16 gather) + self-loop + ReLU + fused linear ----------
__global__ __launch_bounds__(256) void k_agg(const unsigned int* __restrict__ xwb,
                                             const int* __restrict__ off,
                                             const int2* __restrict__ ep,
                                             const float* __restrict__ dinv,
                                             const float* __restrict__ Wlin,
                                             const float* __restrict__ blin,
                                             float* __restrict__ out, int N) {
    int wave = threadIdx.x >> 6;
    int lane = threadIdx.x & 63;
    int c = blockIdx.x * 4 + wave;
    if (c >= N) return;
    int start = off[c];
    int end = off[c + 1];

    float2 acc[8];
    #pragma unroll
    for (int u = 0; u < 8; ++u) acc[u] = make_float2(0.f, 0.f);
    {
        // self-loop: + xw'[c]  (xw' rows pre-scaled by dinv[r])
        unsigned int v = xwb[(long long)c * 64 + lane];
        acc[0].x = __uint_as_float(v << 16);
        acc[0].y = __uint_as_float(v & 0xFFFF0000u);
    }
    for (int k = start; k < end; k += 8) {
        int2 e[8];
        #pragma unroll
        for (int u = 0; u < 8; ++u)
            if (k + u < end) e[u] = ep[k + u];
        #pragma unroll
        for (int u = 0; u < 8; ++u) {
            if (k + u < end) {
                unsigned int v = xwb[(long long)e[u].x * 64 + lane];
                float w = __int_as_float(e[u].y);
                acc[u].x += w * __uint_as_float(v << 16);
                acc[u].y += w * __uint_as_float(v & 0xFFFF0000u);
            }
        }
    }
    float di = dinv[c];
    float2 h;
    h.x = (((acc[0].x + acc[1].x) + (acc[2].x + acc[3].x)) +
           ((acc[4].x + acc[5].x) + (acc[6].x + acc[7].x))) * di;
    h.y = (((acc[0].y + acc[1].y) + (acc[2].y + acc[3].y)) +
           ((acc[4].y + acc[5].y) + (acc[6].y + acc[7].y))) * di;
    h.x = fmaxf(h.x, 0.f);
    h.y = fmaxf(h.y, 0.f);

    const float2* Wl2 = (const float2*)Wlin;
    float p[8];
    #pragma unroll
    for (int t = 0; t < 8; ++t) {
        float2 wv = Wl2[t * 64 + lane];
        p[t] = h.x * wv.x + h.y * wv.y;
    }
    #pragma unroll
    for (int t = 0; t < 8; ++t) {
        #pragma unroll
        for (int s = 1; s < 64; s <<= 1) p[t] += __shfl_xor(p[t], s, 64);
    }
    #pragma unroll
    for (int t = 0; t < 8; ++t)
        if (lane == t) out[(long long)c * 8 + t] = p[t] + blin[t];
}

// ---------- launch ----------
extern "C" void kernel_launch(void* const* d_in, const int* in_sizes, int n_in,
                              void* d_out, int out_size, void* d_ws, size_t ws_size,
                              hipStream_t stream) {
    const float* x    = (const float*)d_in[0];
    const int*   ei   = (const int*)d_in[1];
    const float* ew   = (const float*)d_in[2];
    const float* W0   = (const float*)d_in[3];
    const float* Wih  = (const float*)d_in[4];
    const float* Whh  = (const float*)d_in[5];
    const float* bih  = (const float*)d_in[6];
    const float* bhh  = (const float*)d_in[7];
    const float* Wlin = (const float*)d_in[8];
    const float* blin = (const float*)d_in[9];
    int N = in_sizes[0] / F;   // 50000
    int E = in_sizes[1] / 2;   // 800000
    float* outp = (float*)d_out;

    int nblk = (N + 255) / 256;

    char* wsb = (char*)d_ws;
    size_t cur = 0;
    auto alloc = [&](size_t sz) -> void* {
        void* p = wsb + cur;
        cur = (cur + sz + 255) & ~(size_t)255;
        return p;
    };
    unsigned long long* packed = (unsigned long long*)alloc((size_t)N * 8);
    float* dinv = (float*)alloc((size_t)N * 4);
    int*   off  = (int*)  alloc((size_t)(N + 1) * 4);
    int*   bsum = (int*)  alloc((size_t)nblk * 4);
    int*   flag = (int*)  alloc(256);
    int*   pos  = (int*)  alloc((size_t)E * 4);
    int2*  ep   = (int2*) alloc((size_t)E * 8);
    float* W    = (float*)alloc((size_t)F * F * 4);
    unsigned int* xwb = (unsigned int*)alloc((size_t)N * 64 * 4);  // bf16 x2 per uint
    (void)ws_size; (void)n_in; (void)out_size;

    hipLaunchKernelGGL(k_init,   dim3(nblk),            dim3(256),  0, stream, packed, flag, ei, N);
    hipLaunchKernelGGL(k_count,  dim3((E + 255) / 256), dim3(256),  0, stream, ei, ew, packed, pos, flag, E);
    hipLaunchKernelGGL(k_bsum,   dim3(nblk),            dim3(256),  0, stream, packed, bsum, N);
    hipLaunchKernelGGL(k_bscan,  dim3(1),               dim3(1024), 0, stream, bsum, nblk);
    hipLaunchKernelGGL(k_offs,   dim3(nblk),            dim3(256),  0, stream, packed, bsum, off, dinv, N, E);
    hipLaunchKernelGGL(k_place,  dim3((E + 255) / 256), dim3(256),  0, stream, ei, ew, off, pos, ep, flag, E);
    hipLaunchKernelGGL(k_evolve, dim3(F),               dim3(F),    0, stream, W0, Wih, Whh, bih, bhh, W);
    hipLaunchKernelGGL(k_xw,     dim3(512),             dim3(256),  0, stream, x, W, dinv, xwb, N);
    hipLaunchKernelGGL(k_agg,    dim3((N + 3) / 4),     dim3(256),  0, stream, xwb, off, ep, dinv, Wlin, blin, outp, N);
}

// Round 5
// 245.030 us; speedup vs baseline: 1.7943x; 1.1203x over previous
//
#include <hip/hip_runtime.h>
#include <math.h>

#define F 128
#define FIX_SCALE 16777216.0f          // 2^24
#define FIX_INV   (1.0f / 16777216.0f)
#define CNT_SHIFT 40
#define DEG_MASK  ((1ULL << 40) - 1)

using bf16x8 = __attribute__((ext_vector_type(8))) short;
using f32x4  = __attribute__((ext_vector_type(4))) float;

// ---------- helpers ----------
__device__ inline int read_idx(const int* ei, long long elem, int i64) {
    return i64 ? (int)((const long long*)ei)[elem] : ei[elem];
}
__device__ inline unsigned int f2bf_rn(float f) {   // fp32 -> bf16 bits, round-nearest-even
    unsigned int b = __float_as_uint(f);
    return (b + 0x7FFFu + ((b >> 16) & 1u)) >> 16;
}
__device__ inline float bflo(unsigned int u) { return __uint_as_float(u << 16); }
__device__ inline float bfhi(unsigned int u) { return __uint_as_float(u & 0xFFFF0000u); }

// ---------- K1: zero packed counters, detect index dtype ----------
__global__ void k_init(unsigned long long* packed, int* flag, const int* ei, int N) {
    int i = blockIdx.x * blockDim.x + threadIdx.x;
    if (i < N) packed[i] = 0ULL;
    if (i == 0) {
        int i64 = 1;
        for (int j = 0; j < 32; ++j) if (ei[2 * j + 1] != 0) { i64 = 0; break; }
        *flag = i64;
    }
}

// ---------- K2: ONE packed 64-bit atomic per edge: count + fixed-point deg; pos = old count ----------
__global__ void k_count(const int* ei, const float* ew, unsigned long long* packed,
                        int* pos, const int* flag, int E) {
    int e = blockIdx.x * blockDim.x + threadIdx.x;
    if (e >= E) return;
    int i64 = *flag;
    int c = read_idx(ei, (long long)E + e, i64);
    unsigned long long u = (1ULL << CNT_SHIFT) |
                           (unsigned long long)(ew[e] * FIX_SCALE + 0.5f);
    unsigned long long old = atomicAdd(&packed[c], u);
    pos[e] = (int)(old >> CNT_SHIFT);
}

// ---------- K3a: per-block sums of cnt ----------
__global__ void k_bsum(const unsigned long long* __restrict__ packed,
                       int* __restrict__ bsum, int N) {
    __shared__ int s[4];
    int i = blockIdx.x * 256 + threadIdx.x;
    int v = (i < N) ? (int)(packed[i] >> CNT_SHIFT) : 0;
    #pragma unroll
    for (int o = 1; o < 64; o <<= 1) v += __shfl_xor(v, o, 64);
    if ((threadIdx.x & 63) == 0) s[threadIdx.x >> 6] = v;
    __syncthreads();
    if (threadIdx.x == 0) bsum[blockIdx.x] = s[0] + s[1] + s[2] + s[3];
}

// ---------- K3b: exclusive scan of bsum (nblk ~ 196), one block ----------
__global__ void k_bscan(int* bsum, int nb) {
    __shared__ int sdata[1024];
    int tid = threadIdx.x;
    int run = 0;
    for (int base = 0; base < nb; base += 1024) {
        int i = base + tid;
        int v = (i < nb) ? bsum[i] : 0;
        sdata[tid] = v;
        __syncthreads();
        #pragma unroll
        for (int s = 1; s < 1024; s <<= 1) {
            int add = (tid >= s) ? sdata[tid - s] : 0;
            __syncthreads();
            sdata[tid] += add;
            __syncthreads();
        }
        if (i < nb) bsum[i] = run + sdata[tid] - v;  // exclusive
        run += sdata[1023];
        __syncthreads();
    }
}

// ---------- K3c: off = exclusive CSR offsets; dinv = rsqrt(1 + deg) ----------
__global__ void k_offs(const unsigned long long* __restrict__ packed,
                       const int* __restrict__ bsum,
                       int* __restrict__ off, float* __restrict__ dinv, int N, int E) {
    __shared__ int sdata[256];
    int t = threadIdx.x;
    int i = blockIdx.x * 256 + t;
    unsigned long long p = (i < N) ? packed[i] : 0ULL;
    int v = (int)(p >> CNT_SHIFT);
    sdata[t] = v;
    __syncthreads();
    #pragma unroll
    for (int s = 1; s < 256; s <<= 1) {
        int add = (t >= s) ? sdata[t - s] : 0;
        __syncthreads();
        sdata[t] += add;
        __syncthreads();
    }
    if (i < N) {
        off[i] = bsum[blockIdx.x] + sdata[t] - v;  // exclusive
        float deg = 1.0f + (float)(p & DEG_MASK) * FIX_INV;  // +1 self-loop
        dinv[i] = rsqrtf(deg);
        if (i == N - 1) off[N] = E;
    }
}

// ---------- K5: atomic-free, gather-free placement: ep = (row, raw ew) ----------
__global__ void k_place(const int* ei, const float* ew,
                        const int* __restrict__ off, const int* __restrict__ pos,
                        int2* ep, const int* flag, int E) {
    int e = blockIdx.x * blockDim.x + threadIdx.x;
    if (e >= E) return;
    int i64 = *flag;
    int r = read_idx(ei, e, i64);
    int c = read_idx(ei, (long long)E + e, i64);
    ep[off[c] + pos[e]] = make_int2(r, __float_as_int(ew[e]));
}

// ---------- K6: GRU weight evolution -> transposed split-bf16 W ----------
// Wt[n][k] = W[k][n]; hi = bf16(W), lo = bf16(W - hi). B-fragment-friendly layout.
__global__ void k_evolve(const float* __restrict__ W0, const float* __restrict__ Wih,
                         const float* __restrict__ Whh, const float* __restrict__ bih,
                         const float* __restrict__ bhh,
                         unsigned short* __restrict__ Wth,
                         unsigned short* __restrict__ Wtl) {
    __shared__ __align__(16) float w0row[F];
    int i = blockIdx.x;      // k index (row of W)
    int j = threadIdx.x;     // n index (col of W)
    w0row[j] = W0[i * F + j];
    __syncthreads();
    float air = 0, aiz = 0, ain = 0, ahr = 0, ahz = 0, ahn = 0;
    const float* ir_p = Wih + (size_t)j * F;
    const float* iz_p = Wih + (size_t)(j + F) * F;
    const float* in_p = Wih + (size_t)(j + 2 * F) * F;
    const float* hr_p = Whh + (size_t)j * F;
    const float* hz_p = Whh + (size_t)(j + F) * F;
    const float* hn_p = Whh + (size_t)(j + 2 * F) * F;
    for (int k = 0; k < F; k += 4) {
        float4 w0 = *(const float4*)&w0row[k];
        float4 a;
        a = *(const float4*)&ir_p[k]; air += w0.x*a.x + w0.y*a.y + w0.z*a.z + w0.w*a.w;
        a = *(const float4*)&iz_p[k]; aiz += w0.x*a.x + w0.y*a.y + w0.z*a.z + w0.w*a.w;
        a = *(const float4*)&in_p[k]; ain += w0.x*a.x + w0.y*a.y + w0.z*a.z + w0.w*a.w;
        a = *(const float4*)&hr_p[k]; ahr += w0.x*a.x + w0.y*a.y + w0.z*a.z + w0.w*a.w;
        a = *(const float4*)&hz_p[k]; ahz += w0.x*a.x + w0.y*a.y + w0.z*a.z + w0.w*a.w;
        a = *(const float4*)&hn_p[k]; ahn += w0.x*a.x + w0.y*a.y + w0.z*a.z + w0.w*a.w;
    }
    air += bih[j];         ahr += bhh[j];
    aiz += bih[j + F];     ahz += bhh[j + F];
    ain += bih[j + 2*F];   ahn += bhh[j + 2*F];
    float r = 1.0f / (1.0f + expf(-(air + ahr)));
    float z = 1.0f / (1.0f + expf(-(aiz + ahz)));
    float n = tanhf(ain + r * ahn);
    float w = (1.0f - z) * n + z * w0row[j];
    unsigned int hb = f2bf_rn(w);
    float whi = __uint_as_float(hb << 16);
    unsigned int lb = f2bf_rn(w - whi);
    Wth[j * F + i] = (unsigned short)hb;
    Wtl[j * F + i] = (unsigned short)lb;
}

// ---------- K7: xs = bf16(dinv[r] * x[r])  (pre-scaled, packed 2 bf16/uint) ----------
__global__ void k_cast(const float2* __restrict__ x2, const float* __restrict__ dinv,
                       unsigned int* __restrict__ xs, int M /* N*64 */) {
    int id = blockIdx.x * 256 + threadIdx.x;
    if (id >= M) return;
    float di = dinv[id >> 6];
    float2 v = x2[id];
    xs[id] = f2bf_rn(di * v.x) | (f2bf_rn(di * v.y) << 16);
}

// ---------- K8: aggregation on xs: hagg[c] = bf16( dinv[c] * (xs[c] + sum ew*xs[r]) ) ----------
// 4 edges per gather instruction: 16-lane groups x uint4 (8 features/lane).
__global__ __launch_bounds__(256) void k_agg2(const uint4* __restrict__ xs4,
                                              const int* __restrict__ off,
                                              const int2* __restrict__ ep,
                                              const float* __restrict__ dinv,
                                              uint4* __restrict__ hagg4, int N) {
    int wave = threadIdx.x >> 6, lane = threadIdx.x & 63;
    int c = blockIdx.x * 4 + wave;
    if (c >= N) return;
    int g = lane >> 4, sl = lane & 15;
    int start = off[c], end = off[c + 1];
    float a0[8] = {0,0,0,0,0,0,0,0}, a1[8] = {0,0,0,0,0,0,0,0};
    if (g == 0) {   // self-loop (raw weight 1)
        uint4 v = xs4[(size_t)c * 16 + sl];
        a0[0] = bflo(v.x); a0[1] = bfhi(v.x);
        a0[2] = bflo(v.y); a0[3] = bfhi(v.y);
        a0[4] = bflo(v.z); a0[5] = bfhi(v.z);
        a0[6] = bflo(v.w); a0[7] = bfhi(v.w);
    }
    for (int k = start; k < end; k += 8) {
        int iA = k + g, iB = k + g + 4;
        bool okA = iA < end, okB = iB < end;
        int2 eA, eB;
        if (okA) eA = ep[iA];
        if (okB) eB = ep[iB];
        if (okA) {
            uint4 v = xs4[(size_t)eA.x * 16 + sl];
            float w = __int_as_float(eA.y);
            a0[0] += w * bflo(v.x); a0[1] += w * bfhi(v.x);
            a0[2] += w * bflo(v.y); a0[3] += w * bfhi(v.y);
            a0[4] += w * bflo(v.z); a0[5] += w * bfhi(v.z);
            a0[6] += w * bflo(v.w); a0[7] += w * bfhi(v.w);
        }
        if (okB) {
            uint4 v = xs4[(size_t)eB.x * 16 + sl];
            float w = __int_as_float(eB.y);
            a1[0] += w * bflo(v.x); a1[1] += w * bfhi(v.x);
            a1[2] += w * bflo(v.y); a1[3] += w * bfhi(v.y);
            a1[4] += w * bflo(v.z); a1[5] += w * bfhi(v.z);
            a1[6] += w * bflo(v.w); a1[7] += w * bfhi(v.w);
        }
    }
    #pragma unroll
    for (int f = 0; f < 8; ++f) {
        float v = a0[f] + a1[f];
        v += __shfl_xor(v, 16, 64);
        v += __shfl_xor(v, 32, 64);
        a0[f] = v;
    }
    if (lane < 16) {
        float di = dinv[c];
        uint4 o;
        o.x = f2bf_rn(di * a0[0]) | (f2bf_rn(di * a0[1]) << 16);
        o.y = f2bf_rn(di * a0[2]) | (f2bf_rn(di * a0[3]) << 16);
        o.z = f2bf_rn(di * a0[4]) | (f2bf_rn(di * a0[5]) << 16);
        o.w = f2bf_rn(di * a0[6]) | (f2bf_rn(di * a0[7]) << 16);
        hagg4[(size_t)c * 16 + lane] = o;
    }
}

// ---------- K9: out = relu(hagg @ W) @ Wlin^T + blin  (MFMA, split-bf16 W) ----------
__global__ __launch_bounds__(256) void k_gemm(const uint4* __restrict__ hagg4,
                                              const unsigned short* __restrict__ Wth,
                                              const unsigned short* __restrict__ Wtl,
                                              const float* __restrict__ Wlin,
                                              const float* __restrict__ blin,
                                              float* __restrict__ out, int N) {
    __shared__ __align__(16) unsigned int At[64 * 68];  // 64 rows bf16x128, stride padded 68 uints
    __shared__ __align__(16) float WlinL[8 * F];
    int t = threadIdx.x;
    int row0 = blockIdx.x * 64;
    #pragma unroll
    for (int it = 0; it < 4; ++it) {
        int idx = it * 256 + t;          // 1024 uint4 slots
        int rr = idx >> 4, c4 = idx & 15;
        uint4 v = make_uint4(0u, 0u, 0u, 0u);
        if (row0 + rr < N) v = hagg4[(size_t)(row0 + rr) * 16 + c4];
        *(uint4*)&At[rr * 68 + c4 * 4] = v;
    }
    *(float4*)&WlinL[t * 4] = *(const float4*)&Wlin[t * 4];   // 1024 floats
    __syncthreads();

    int wave = t >> 6, lane = t & 63;
    int sl = lane & 15, q = lane >> 4;
    const unsigned short* Ash = (const unsigned short*)At;
    int mrow = wave * 16 + sl;           // A-row within tile (m = lane&15)

    f32x4 acc[8];
    #pragma unroll
    for (int nt = 0; nt < 8; ++nt) acc[nt] = (f32x4){0.f, 0.f, 0.f, 0.f};
    #pragma unroll
    for (int ko = 0; ko < 4; ++ko) {
        bf16x8 a = *(const bf16x8*)&Ash[mrow * 136 + ko * 32 + q * 8];
        #pragma unroll
        for (int nt = 0; nt < 8; ++nt) {
            int boff = (nt * 16 + sl) * F + ko * 32 + q * 8;
            bf16x8 bh = *(const bf16x8*)&Wth[boff];
            bf16x8 bl = *(const bf16x8*)&Wtl[boff];
            acc[nt] = __builtin_amdgcn_mfma_f32_16x16x32_bf16(a, bh, acc[nt], 0, 0, 0);
            acc[nt] = __builtin_amdgcn_mfma_f32_16x16x32_bf16(a, bl, acc[nt], 0, 0, 0);
        }
    }
    // relu (C layout: row = q*4+reg, col = nt*16+sl)
    #pragma unroll
    for (int nt = 0; nt < 8; ++nt)
        #pragma unroll
        for (int r = 0; r < 4; ++r) acc[nt][r] = fmaxf(acc[nt][r], 0.f);

    // fp32 projection: p[t][reg] = sum_col relu(S)[row][col] * Wlin[t][col]
    float p[8][4];
    #pragma unroll
    for (int tt = 0; tt < 8; ++tt) {
        float wl[8];
        #pragma unroll
        for (int nt = 0; nt < 8; ++nt) wl[nt] = WlinL[tt * F + nt * 16 + sl];
        #pragma unroll
        for (int r = 0; r < 4; ++r) {
            float s = 0.f;
            #pragma unroll
            for (int nt = 0; nt < 8; ++nt) s += acc[nt][r] * wl[nt];
            p[tt][r] = s;
        }
    }
    #pragma unroll
    for (int tt = 0; tt < 8; ++tt)
        #pragma unroll
        for (int r = 0; r < 4; ++r) {
            float v = p[tt][r];
            v += __shfl_xor(v, 1, 64); v += __shfl_xor(v, 2, 64);
            v += __shfl_xor(v, 4, 64); v += __shfl_xor(v, 8, 64);
            p[tt][r] = v;
        }
    if (sl == 0) {
        #pragma unroll
        for (int r = 0; r < 4; ++r) {
            int row = row0 + wave * 16 + q * 4 + r;
            if (row < N) {
                #pragma unroll
                for (int tt = 0; tt < 8; ++tt)
                    out[(size_t)row * 8 + tt] = p[tt][r] + blin[tt];
            }
        }
    }
}

// ---------- launch ----------
extern "C" void kernel_launch(void* const* d_in, const int* in_sizes, int n_in,
                              void* d_out, int out_size, void* d_ws, size_t ws_size,
                              hipStream_t stream) {
    const float* x    = (const float*)d_in[0];
    const int*   ei   = (const int*)d_in[1];
    const float* ew   = (const float*)d_in[2];
    const float* W0   = (const float*)d_in[3];
    const float* Wih  = (const float*)d_in[4];
    const float* Whh  = (const float*)d_in[5];
    const float* bih  = (const float*)d_in[6];
    const float* bhh  = (const float*)d_in[7];
    const float* Wlin = (const float*)d_in[8];
    const float* blin = (const float*)d_in[9];
    int N = in_sizes[0] / F;   // 50000
    int E = in_sizes[1] / 2;   // 800000
    float* outp = (float*)d_out;

    int nblk = (N + 255) / 256;

    char* wsb = (char*)d_ws;
    size_t cur = 0;
    auto alloc = [&](size_t sz) -> void* {
        void* p = wsb + cur;
        cur = (cur + sz + 255) & ~(size_t)255;
        return p;
    };
    unsigned long long* packed = (unsigned long long*)alloc((size_t)N * 8);
    float* dinv = (float*)alloc((size_t)N * 4);
    int*   off  = (int*)  alloc((size_t)(N + 1) * 4);
    int*   bsum = (int*)  alloc((size_t)nblk * 4);
    int*   flag = (int*)  alloc(256);
    int*   pos  = (int*)  alloc((size_t)E * 4);
    int2*  ep   = (int2*) alloc((size_t)E * 8);
    unsigned short* Wth = (unsigned short*)alloc((size_t)F * F * 2);
    unsigned short* Wtl = (unsigned short*)alloc((size_t)F * F * 2);
    unsigned int* xs    = (unsigned int*)alloc((size_t)N * 64 * 4);
    unsigned int* hagg  = (unsigned int*)alloc((size_t)N * 64 * 4);
    (void)ws_size; (void)n_in; (void)out_size;

    int M = N * 64;
    hipLaunchKernelGGL(k_init,   dim3(nblk),            dim3(256),  0, stream, packed, flag, ei, N);
    hipLaunchKernelGGL(k_count,  dim3((E + 255) / 256), dim3(256),  0, stream, ei, ew, packed, pos, flag, E);
    hipLaunchKernelGGL(k_bsum,   dim3(nblk),            dim3(256),  0, stream, packed, bsum, N);
    hipLaunchKernelGGL(k_bscan,  dim3(1),               dim3(1024), 0, stream, bsum, nblk);
    hipLaunchKernelGGL(k_offs,   dim3(nblk),            dim3(256),  0, stream, packed, bsum, off, dinv, N, E);
    hipLaunchKernelGGL(k_evolve, dim3(F),               dim3(F),    0, stream, W0, Wih, Whh, bih, bhh, Wth, Wtl);
    hipLaunchKernelGGL(k_place,  dim3((E + 255) / 256), dim3(256),  0, stream, ei, ew, off, pos, ep, flag, E);
    hipLaunchKernelGGL(k_cast,   dim3((M + 255) / 256), dim3(256),  0, stream, (const float2*)x, dinv, xs, M);
    hipLaunchKernelGGL(k_agg2,   dim3((N + 3) / 4),     dim3(256),  0, stream, (const uint4*)xs, off, ep, dinv, (uint4*)hagg, N);
    hipLaunchKernelGGL(k_gemm,   dim3((N + 63) / 64),   dim3(256),  0, stream, (const uint4*)hagg, Wth, Wtl, Wlin, blin, outp, N);
}